// Round 15
// baseline (3206.449 us; speedup 1.0000x reference)
//
#include <hip/hip_runtime.h>
#include <stdint.h>

#define T_ 50

typedef float f32x4 __attribute__((ext_vector_type(4)));
typedef short s16x8 __attribute__((ext_vector_type(8)));

// ---------------- workspace byte offsets ----------------
// WIH/WHH packed per 8-wave x 2-unit-tile decomposition:
//   off = w*32768 + ut*16384 + gate*4096 + ks*512 + l15*32 + g*8 + j
// WINIT: off = w*16384 + sel*8192 + ut*4096 + ks*512 + l15*32 + g*8 + j
// WFC:   off = w*8192  + ut*4096 + ks*512 + l15*32 + g*8 + j
#define WS_WIH   0u          // 262144 elems
#define WS_WHH   524288u     // 262144 elems
#define WS_WINIT 1048576u    // 131072 elems
#define WS_WFC   1310720u    // 65536 elems
#define WS_GPAD  1441792u    // [32][32] bf16 zero-padded G
#define WS_NEED  1443840u

// ---------------- LDS byte offsets (dynamic, 78592 B) ----------------
#define L_A1   0             // [24][256] bf16 swizzled (Gh)
#define L_A2   24576         // [24][256] bf16 swizzled (Gx)
#define L_XL   49152         // [24][260] bf16 x tile
#define L_ZR   61696         // [256] bf16 zero row
#define L_HST  62208         // [256 unit][32 node] bf16 h stage
#define L_TOT  78592

__device__ __forceinline__ f32x4 mfma16(s16x8 a, s16x8 b, f32x4 c){
  return __builtin_amdgcn_mfma_f32_16x16x32_bf16(a, b, c, 0, 0, 0);
}
__device__ __forceinline__ uint32_t bfbits(float f){
  uint32_t u = __builtin_bit_cast(uint32_t, f);
  u += 0x7FFFu + ((u >> 16) & 1u);   // RNE
  return u >> 16;
}
__device__ __forceinline__ uint32_t pk2bf(float lo, float hi){
  return bfbits(lo) | (bfbits(hi) << 16);
}
#define LOG2E 1.4426950408889634f
__device__ __forceinline__ float fexp2(float x){ return __builtin_amdgcn_exp2f(x); }
__device__ __forceinline__ float frcp_(float x){ return __builtin_amdgcn_rcpf(x); }
__device__ __forceinline__ float fsig(float x){ return frcp_(1.f + fexp2(-LOG2E * x)); }
__device__ __forceinline__ float ftanh_(float x){ return 1.f - 2.f * frcp_(1.f + fexp2(2.f * LOG2E * x)); }

// ---------------- prep: f32 -> bf16, fragment-packed ----------------
__global__ void prep_kernel(const float* __restrict__ G,
                            const float* __restrict__ Wih, const float* __restrict__ Whh,
                            const float* __restrict__ Wh1, const float* __restrict__ Wh2,
                            const float* __restrict__ Wfc, uint8_t* __restrict__ ws)
{
  const int tid = blockIdx.x * blockDim.x + threadIdx.x;
  const int nth = gridDim.x * blockDim.x;
  uint16_t* wih = (uint16_t*)(ws + WS_WIH);
  uint16_t* whh = (uint16_t*)(ws + WS_WHH);
  uint16_t* wini= (uint16_t*)(ws + WS_WINIT);
  uint16_t* wfc = (uint16_t*)(ws + WS_WFC);
  uint16_t* gp  = (uint16_t*)(ws + WS_GPAD);

  for (int i = tid; i < 262144; i += nth){
    int row = i >> 8, col = i & 255;
    int gt = row >> 8, u = row & 255;
    int ut = u >> 7, wv = (u >> 4) & 7, l15 = u & 15;
    int ks = col >> 5, gg = (col >> 3) & 3, j = col & 7;
    int off = wv*32768 + ut*16384 + gt*4096 + ks*512 + l15*32 + gg*8 + j;
    wih[off] = (uint16_t)bfbits(Wih[i]);
    whh[off] = (uint16_t)bfbits(Whh[i]);
  }
  for (int i = tid; i < 131072; i += nth){
    int row = i >> 8, col = i & 255;
    int sel = row >> 8, u = row & 255;
    int ut = u >> 7, wv = (u >> 4) & 7, l15 = u & 15;
    int ks = col >> 5, gg = (col >> 3) & 3, j = col & 7;
    int off = wv*16384 + sel*8192 + ut*4096 + ks*512 + l15*32 + gg*8 + j;
    float v = (sel == 0) ? Wh1[u*256 + col] : Wh2[u*256 + col];
    wini[off] = (uint16_t)bfbits(v);
  }
  for (int i = tid; i < 65536; i += nth){
    int u = i >> 8, col = i & 255;
    int ut = u >> 7, wv = (u >> 4) & 7, l15 = u & 15;
    int ks = col >> 5, gg = (col >> 3) & 3, j = col & 7;
    int off = wv*8192 + ut*4096 + ks*512 + l15*32 + gg*8 + j;
    wfc[off] = (uint16_t)bfbits(Wfc[i]);
  }
  for (int i = tid; i < 1024; i += nth){
    int n = i >> 5, m = i & 31;
    gp[i] = (n < 24 && m < 24) ? (uint16_t)bfbits(G[n*24 + m]) : (uint16_t)0;
  }
}

// fragment fetch from packed image (base already wave-offset)
#define FRAG(Wb, gt, ut, ks) (*(const s16x8*)&(Wb)[(ut)*16384 + (gt)*4096 + (ks)*512 + lg])

#define LDW8(P, Wb, ks) \
  P##00 = FRAG(Wb,0,0,ks); P##01 = FRAG(Wb,0,1,ks); \
  P##10 = FRAG(Wb,1,0,ks); P##11 = FRAG(Wb,1,1,ks); \
  P##20 = FRAG(Wb,2,0,ks); P##21 = FRAG(Wb,2,1,ks); \
  P##30 = FRAG(Wb,3,0,ks); P##31 = FRAG(Wb,3,1,ks);

#define MMF8(P, ks, r0, r1) { \
  const int kk_ = (ks)*32 + g*8; \
  s16x8 A0_ = *(const s16x8*)&(r0)[kk_ ^ swz0]; \
  s16x8 A1_ = *(const s16x8*)&(r1)[kk_ ^ swz1]; \
  acc000 = mfma16(A0_, P##00, acc000); acc100 = mfma16(A1_, P##00, acc100); \
  acc001 = mfma16(A0_, P##01, acc001); acc101 = mfma16(A1_, P##01, acc101); \
  acc010 = mfma16(A0_, P##10, acc010); acc110 = mfma16(A1_, P##10, acc110); \
  acc011 = mfma16(A0_, P##11, acc011); acc111 = mfma16(A1_, P##11, acc111); \
  acc020 = mfma16(A0_, P##20, acc020); acc120 = mfma16(A1_, P##20, acc120); \
  acc021 = mfma16(A0_, P##21, acc021); acc121 = mfma16(A1_, P##21, acc121); \
  acc030 = mfma16(A0_, P##30, acc030); acc130 = mfma16(A1_, P##30, acc130); \
  acc031 = mfma16(A0_, P##31, acc031); acc131 = mfma16(A1_, P##31, acc131); }

#define ACCZERO() \
  acc000=acc001=acc010=acc011=acc020=acc021=acc030=acc031= \
  acc100=acc101=acc110=acc111=acc120=acc121=acc130=acc131=(f32x4){0,0,0,0};

// depth-2 ping-pong pipelined GEMM phase over ks=0..7
#define GEMM_PHASE(Wb, r0, r1) { \
  s16x8 s00,s01,s10,s11,s20,s21,s30,s31; \
  s16x8 t00,t01,t10,t11,t20,t21,t30,t31; \
  LDW8(s, Wb, 0) LDW8(t, Wb, 1) \
  MMF8(s, 0, r0, r1) LDW8(s, Wb, 2) \
  MMF8(t, 1, r0, r1) LDW8(t, Wb, 3) \
  MMF8(s, 2, r0, r1) LDW8(s, Wb, 4) \
  MMF8(t, 3, r0, r1) LDW8(t, Wb, 5) \
  MMF8(s, 4, r0, r1) LDW8(s, Wb, 6) \
  MMF8(t, 5, r0, r1) LDW8(t, Wb, 7) \
  MMF8(s, 6, r0, r1) \
  MMF8(t, 7, r0, r1) }

// ---------------- one workgroup per batch, 8 waves x 2 unit tiles ----------------
__global__ void __launch_bounds__(512, 2)
encoder_kernel(const float* __restrict__ x, const uint8_t* __restrict__ ws,
               float* __restrict__ out,
               const float* __restrict__ bih, const float* __restrict__ bhh,
               const float* __restrict__ bh1, const float* __restrict__ bh2,
               const float* __restrict__ bfc)
{
  extern __shared__ uint8_t smem[];
  uint16_t* A1  = (uint16_t*)(smem + L_A1);
  uint16_t* A2  = (uint16_t*)(smem + L_A2);
  uint16_t* XL  = (uint16_t*)(smem + L_XL);
  uint16_t* ZR  = (uint16_t*)(smem + L_ZR);
  uint16_t* HST = (uint16_t*)(smem + L_HST);

  const int tid = threadIdx.x;
  const int b   = blockIdx.x;
  const int w   = tid >> 6;        // wave 0..7
  const int l   = tid & 63;
  const int l15 = l & 15;
  const int g   = l >> 4;
  const int u0  = w*16 + l15;      // unit tile 0
  const int u1  = 128 + u0;        // unit tile 1
  const int lg  = l15*32 + g*8;    // packed-fragment lane offset

  const uint16_t* WIHW  = (const uint16_t*)(ws + WS_WIH)   + w*32768;
  const uint16_t* WHHW  = (const uint16_t*)(ws + WS_WHH)   + w*32768;
  const uint16_t* WINIW = (const uint16_t*)(ws + WS_WINIT) + w*16384;
  const uint16_t* WFCW  = (const uint16_t*)(ws + WS_WFC)   + w*8192;
  const uint16_t* GP    = (const uint16_t*)(ws + WS_GPAD);

  for (int i = tid; i < 256;  i += 512) ZR[i] = 0;
  for (int i = tid; i < 8192; i += 512) HST[i] = 0;   // node-pad 24-31 vs NaN

  // G A-fragments for both node tiles
  s16x8 gfragM[2];
  gfragM[0] = *(const s16x8*)&GP[(l15     )*32 + g*8];
  gfragM[1] = *(const s16x8*)&GP[(l15 + 16)*32 + g*8];

  float bbv[4][2], bh1l[2], bh2l[2], bfcl[2];
  #pragma unroll
  for (int ut = 0; ut < 2; ut++){
    int u = ut ? u1 : u0;
    #pragma unroll
    for (int gt = 0; gt < 4; gt++) bbv[gt][ut] = bih[gt*256+u] + bhh[gt*256+u];
    bh1l[ut] = bh1[u]; bh2l[ut] = bh2[u]; bfcl[ut] = bfc[u];
  }

  // A-fragment row pointers (Mt=0 rows 0-15; Mt=1 rows 16-31, >=24 -> ZR)
  const int r1v = (16 + l15) < 24;
  const uint16_t* a1r0 = A1 + l15*256;
  const uint16_t* a1r1 = r1v ? (A1 + (16+l15)*256) : ZR;
  const uint16_t* a2r0 = A2 + l15*256;
  const uint16_t* a2r1 = r1v ? (A2 + (16+l15)*256) : ZR;
  const int swz0 = (l15 & 7) << 3;
  const int swz1 = r1v ? (((16+l15) & 7) << 3) : 0;

  // named accumulators acc{Mt}{gate}{ut}
  f32x4 acc000,acc001,acc010,acc011,acc020,acc021,acc030,acc031;
  f32x4 acc100,acc101,acc110,acc111,acc120,acc121,acc130,acc131;

  // x tile: 6144 f32, 12 per thread as 3x f32x4 (issue-early/write-late)
  auto xld_issue = [&](const float* xt, f32x4 xv[3]){
    #pragma unroll
    for (int p = 0; p < 3; p++)
      xv[p] = *(const f32x4*)(xt + tid*4 + p*2048);
  };
  auto xld_write = [&](const f32x4 xv[3]){
    #pragma unroll
    for (int p = 0; p < 3; p++){
      int e = tid*4 + p*2048;
      int m = e >> 8, f = e & 255;
      uint2 pk; pk.x = pk2bf(xv[p][0], xv[p][1]); pk.y = pk2bf(xv[p][2], xv[p][3]);
      *(uint2*)&XL[m*260 + f] = pk;
    }
  };

  // Gx[t]: both unit tiles, both node tiles -> A2 swizzled
  auto gx_stage = [&](){
    #pragma unroll
    for (int ut = 0; ut < 2; ut++){
      int u = ut ? u1 : u0;
      s16x8 bfrag = (s16x8){0,0,0,0,0,0,0,0};
      if (g < 3){
        #pragma unroll
        for (int j = 0; j < 8; j++)
          bfrag[j] = (short)XL[(g*8 + j)*260 + u];
      }
      #pragma unroll
      for (int Mt = 0; Mt < 2; Mt++){
        f32x4 zz = {0.f,0.f,0.f,0.f};
        f32x4 gx = mfma16(gfragM[Mt], bfrag, zz);
        int n0 = Mt*16 + g*4;
        if (n0 < 24){
          uint32_t a01 = pk2bf(gx[0], gx[1]), a23 = pk2bf(gx[2], gx[3]);
          A2[(n0  )*256 + (u ^ (((n0  )&7)<<3))] = (uint16_t)a01;
          A2[(n0+1)*256 + (u ^ (((n0+1)&7)<<3))] = (uint16_t)(a01>>16);
          A2[(n0+2)*256 + (u ^ (((n0+2)&7)<<3))] = (uint16_t)a23;
          A2[(n0+3)*256 + (u ^ (((n0+3)&7)<<3))] = (uint16_t)(a23>>16);
        }
      }
    }
  };

  // Gh from HST -> A1 swizzled, both unit tiles
  auto gh_stage = [&](){
    #pragma unroll
    for (int ut = 0; ut < 2; ut++){
      int u = ut ? u1 : u0;
      s16x8 hb = *(const s16x8*)&HST[u*32 + g*8];
      #pragma unroll
      for (int Mt = 0; Mt < 2; Mt++){
        f32x4 zz = {0.f,0.f,0.f,0.f};
        f32x4 gh = mfma16(gfragM[Mt], hb, zz);
        int n0 = Mt*16 + g*4;
        if (n0 < 24){
          uint32_t a01 = pk2bf(gh[0], gh[1]), a23 = pk2bf(gh[2], gh[3]);
          A1[(n0  )*256 + (u ^ (((n0  )&7)<<3))] = (uint16_t)a01;
          A1[(n0+1)*256 + (u ^ (((n0+1)&7)<<3))] = (uint16_t)(a01>>16);
          A1[(n0+2)*256 + (u ^ (((n0+2)&7)<<3))] = (uint16_t)a23;
          A1[(n0+3)*256 + (u ^ (((n0+3)&7)<<3))] = (uint16_t)(a23>>16);
        }
      }
    }
  };

  float cst[2][2][4];              // [ut][Mt][r]
  const float* xb = x + (size_t)b * T_ * 6144;

  // ---------- init ----------
  {
    f32x4 xv[3];
    xld_issue(xb, xv);
    xld_write(xv);
  }
  __syncthreads();                 // XL = x0
  gx_stage();                      // A2 = Gx0
  __syncthreads();
  {
    f32x4 h0a[2][2] = {}, c0a[2][2] = {};   // [Mt][ut]
    ACCZERO()
    #pragma unroll
    for (int ks = 0; ks < 8; ks++){
      const int kk = ks*32 + g*8;
      s16x8 a0 = *(const s16x8*)&a2r0[kk ^ swz0];
      s16x8 a1 = *(const s16x8*)&a2r1[kk ^ swz1];
      s16x8 b10 = *(const s16x8*)&WINIW[        0*4096 + ks*512 + lg];
      s16x8 b11 = *(const s16x8*)&WINIW[        1*4096 + ks*512 + lg];
      s16x8 b20 = *(const s16x8*)&WINIW[8192 +  0*4096 + ks*512 + lg];
      s16x8 b21 = *(const s16x8*)&WINIW[8192 +  1*4096 + ks*512 + lg];
      h0a[0][0] = mfma16(a0, b10, h0a[0][0]); h0a[1][0] = mfma16(a1, b10, h0a[1][0]);
      h0a[0][1] = mfma16(a0, b11, h0a[0][1]); h0a[1][1] = mfma16(a1, b11, h0a[1][1]);
      c0a[0][0] = mfma16(a0, b20, c0a[0][0]); c0a[1][0] = mfma16(a1, b20, c0a[1][0]);
      c0a[0][1] = mfma16(a0, b21, c0a[0][1]); c0a[1][1] = mfma16(a1, b21, c0a[1][1]);
      s16x8 q00,q01,q10,q11,q20,q21,q30,q31;
      LDW8(q, WIHW, ks)
      MMF8(q, ks, a2r0, a2r1)
    }
    #pragma unroll
    for (int ut = 0; ut < 2; ut++){
      int u = ut ? u1 : u0;
      #pragma unroll
      for (int Mt = 0; Mt < 2; Mt++){
        int n0 = Mt*16 + g*4;
        float hv[4];
        #pragma unroll
        for (int r = 0; r < 4; r++){
          cst[ut][Mt][r] = c0a[Mt][ut][r] + bh2l[ut];
          hv[r]          = h0a[Mt][ut][r] + bh1l[ut];
        }
        if (n0 < 24){
          uint2 p; p.x = pk2bf(hv[0], hv[1]); p.y = pk2bf(hv[2], hv[3]);
          *(uint2*)&HST[u*32 + n0] = p;
        }
      }
    }
  }
  __syncthreads();                 // HST = h0; Gx0 reads done
  gh_stage();                      // A1 = Gh0
  {
    f32x4 xv[3];
    xld_issue(xb + 6144, xv);
    __syncthreads();               // XL free (x0 consumed)
    xld_write(xv);
  }
  __syncthreads();
  gx_stage();                      // A2 = Gx1
  __syncthreads();                 // A1,A2 ready

  // ---------- recurrence: acc holds z_t at loop top ----------
  for (int t = 0; t < T_; t++){
    // u = z_t + Gh_t . W_hh^T   (depth-2 pipelined weight stream)
    GEMM_PHASE(WHHW, a1r0, a1r1)

    // LSTM pointwise -> h to HST  (acc{Mt}{gate}{ut})
    {
      float hv[4];
      #define LSTM_TILE(AI,AF,AG,AO, ut_, Mt_, u_) { \
        _Pragma("unroll") \
        for (int r = 0; r < 4; r++){ \
          float ig = fsig  (AI[r] + bbv[0][ut_]); \
          float fg = fsig  (AF[r] + bbv[1][ut_]); \
          float gg = ftanh_(AG[r] + bbv[2][ut_]); \
          float og = fsig  (AO[r] + bbv[3][ut_]); \
          float c  = fg*cst[ut_][Mt_][r] + ig*gg; \
          cst[ut_][Mt_][r] = c; \
          hv[r] = og*ftanh_(c); \
        } \
        { int n0_ = (Mt_)*16 + g*4; \
          if (n0_ < 24){ \
            uint2 p_; p_.x = pk2bf(hv[0], hv[1]); p_.y = pk2bf(hv[2], hv[3]); \
            *(uint2*)&HST[(u_)*32 + n0_] = p_; } } }
      LSTM_TILE(acc000, acc010, acc020, acc030, 0, 0, u0)
      LSTM_TILE(acc100, acc110, acc120, acc130, 0, 1, u0)
      LSTM_TILE(acc001, acc011, acc021, acc031, 1, 0, u1)
      LSTM_TILE(acc101, acc111, acc121, acc131, 1, 1, u1)
      #undef LSTM_TILE
    }
    __syncthreads();               // B1: HST done; A1 reads done
    gh_stage();                    // A1 = Gh_{t+1}

    if (t+1 < T_){
      int tn = (t+2 < T_) ? (t+2) : (T_-1);
      f32x4 xv[3];
      xld_issue(xb + (size_t)tn*6144, xv);   // x_{t+2}, hides under z-GEMM
      // z_{t+1} = Gx_{t+1} . W_ih^T  (depth-2 pipelined)
      ACCZERO()
      GEMM_PHASE(WIHW, a2r0, a2r1)
      __syncthreads();             // B2: A2/XL reads done; A1 writes done
      xld_write(xv);               // XL = x_{t+2}
      __syncthreads();             // B3: XL ready
      gx_stage();                  // A2 = Gx_{t+2}
    } else {
      __syncthreads();             // B2 (final): A1 writes visible
    }
  }

  // ---------- final: out = tanh(Gh_final . W_fc^T + bfc) ----------
  {
    f32x4 oacc[2][2] = {};         // [Mt][ut]
    #pragma unroll
    for (int ks = 0; ks < 8; ks++){
      const int kk = ks*32 + g*8;
      s16x8 a0 = *(const s16x8*)&a1r0[kk ^ swz0];
      s16x8 a1 = *(const s16x8*)&a1r1[kk ^ swz1];
      s16x8 f0 = *(const s16x8*)&WFCW[          ks*512 + lg];
      s16x8 f1 = *(const s16x8*)&WFCW[4096 +    ks*512 + lg];
      oacc[0][0] = mfma16(a0, f0, oacc[0][0]); oacc[1][0] = mfma16(a1, f0, oacc[1][0]);
      oacc[0][1] = mfma16(a0, f1, oacc[0][1]); oacc[1][1] = mfma16(a1, f1, oacc[1][1]);
    }
    #pragma unroll
    for (int ut = 0; ut < 2; ut++){
      int u = ut ? u1 : u0;
      #pragma unroll
      for (int Mt = 0; Mt < 2; Mt++){
        int n0 = Mt*16 + g*4;
        if (n0 < 24){
          #pragma unroll
          for (int r = 0; r < 4; r++)
            out[(size_t)b*6144 + (n0+r)*256 + u] = ftanh_(oacc[Mt][ut][r] + bfcl[ut]);
        }
      }
    }
  }
}

extern "C" void kernel_launch(void* const* d_in, const int* in_sizes, int n_in,
                              void* d_out, int out_size, void* d_ws, size_t ws_size,
                              hipStream_t stream)
{
  (void)in_sizes; (void)n_in; (void)out_size;
  if (ws_size < WS_NEED) return;   // loud failure via validation rather than OOB

  const float* x   = (const float*)d_in[0];
  const float* G   = (const float*)d_in[1];
  const float* Wih = (const float*)d_in[2];
  const float* bih = (const float*)d_in[3];
  const float* Whh = (const float*)d_in[4];
  const float* bhh = (const float*)d_in[5];
  const float* Wh1 = (const float*)d_in[6];
  const float* bh1 = (const float*)d_in[7];
  const float* Wh2 = (const float*)d_in[8];
  const float* bh2 = (const float*)d_in[9];
  const float* Wfc = (const float*)d_in[10];
  const float* bfc = (const float*)d_in[11];
  uint8_t* ws = (uint8_t*)d_ws;

  hipLaunchKernelGGL(prep_kernel, dim3(256), dim3(256), 0, stream,
                     G, Wih, Whh, Wh1, Wh2, Wfc, ws);

  hipFuncSetAttribute((const void*)encoder_kernel,
                      hipFuncAttributeMaxDynamicSharedMemorySize, L_TOT);
  hipLaunchKernelGGL(encoder_kernel, dim3(64), dim3(512), L_TOT, stream,
                     x, (const uint8_t*)ws, (float*)d_out,
                     bih, bhh, bh1, bh2, bfc);
}